// Round 3
// baseline (1238.752 us; speedup 1.0000x reference)
//
#include <hip/hip_runtime.h>
#include <math.h>

// Problem constants (B=4, C=64, W=64 from reference)
#define PB 4
#define PC 64
#define PW 64
#define PN 4096      // W*W
#define PN2 8192     // 2*N (candidates per batch)
#define QTOT 16384   // B*N queries
#define QPT 8        // queries per thread in knn scan
#define KTILE 256    // candidates staged in LDS per tile
#define POFF1 49152      // 4*3*4096  (res[:, :3] size)
#define POFF2 1048576    // POFF1 + 4*61*4096 (start of depth)
#define OUTSZ 1064960    // POFF2 + 4*4096

// ---- workspace layout (bytes) ----
// pts4 : 0        .. 524288    (B*2N float4: x,y,z,|p|^2)
// lc   : 524288   .. 655360    (B*2N float: log(conf+1e-6))
// zbuf : 655360   .. 720896    (B*N int, float bits, init +inf)
// pixA : 720896   .. 786432    (QTOT int, dest pixel or -1)
// zA   : 786432   .. 851968    (QTOT float, splat z)
// wA   : 851968   .. 1114112   (QTOT float4, softmax weights)
// nnA  : 1114112  .. 1376256   (QTOT int4, neighbor indices)
// psv  : 1376256  .. +ksplit*262144  (float4 partial top-4 dists)
// pid  : after psv .. +ksplit*262144 (int4 partial top-4 idx)

__device__ __forceinline__ void ins4(float s, int idx,
    float& s0, float& s1, float& s2, float& s3,
    int& i0, int& i1, int& i2, int& i3) {
  // caller guarantees s < s3; strict < keeps lowest-index-first tie-break
  if (s < s2) {
    s3 = s2; i3 = i2;
    if (s < s1) {
      s2 = s1; i2 = i1;
      if (s < s0) { s1 = s0; i1 = i0; s0 = s; i0 = idx; }
      else        { s1 = s;  i1 = idx; }
    } else { s2 = s; i2 = idx; }
  } else { s3 = s; i3 = idx; }
}

// Fused: zero output, init zbuf to +inf, unproject both views to world
// points (x,y,z,|p|^2) and log(conf+1e-6).
__global__ __launch_bounds__(256) void k_prep(
    const float* __restrict__ pp1, const float* __restrict__ pp2,
    const float* __restrict__ Kinv,
    const float* __restrict__ RTinv1, const float* __restrict__ RTinv2,
    const float* __restrict__ dc1, const float* __restrict__ dc2,
    float4* __restrict__ pts4, float* __restrict__ lc,
    float* __restrict__ out, int* __restrict__ zbuf) {
  int gid = blockIdx.x * blockDim.x + threadIdx.x;   // 0 .. 32767
  int stride = gridDim.x * blockDim.x;
  for (int j = gid; j < OUTSZ; j += stride) out[j] = 0.0f;
  if (gid < PB * PN) zbuf[gid] = 0x7f800000;          // +inf

  // one world point per thread
  int b = gid >> 13;                 // gid / PN2
  int j = gid & (PN2 - 1);
  int view2 = (j >= PN) ? 1 : 0;
  int jj = view2 ? (j - PN) : j;
  float d = view2 ? pp2[b * PN + jj] : pp1[b * PN + jj];
  float x = (float)(jj & (PW - 1));
  float y = (float)(jj >> 6);
  const float* Ki = Kinv + b * 16;
  const float* Ri = (view2 ? RTinv2 : RTinv1) + b * 16;
  // proj = [x*d, y*d, d, 1]
  float p0 = x * d, p1 = y * d, p2 = d, p3 = 1.0f;
  float t0 = Ki[0]  * p0 + Ki[1]  * p1 + Ki[2]  * p2 + Ki[3]  * p3;
  float t1 = Ki[4]  * p0 + Ki[5]  * p1 + Ki[6]  * p2 + Ki[7]  * p3;
  float t2 = Ki[8]  * p0 + Ki[9]  * p1 + Ki[10] * p2 + Ki[11] * p3;
  float t3 = Ki[12] * p0 + Ki[13] * p1 + Ki[14] * p2 + Ki[15] * p3;
  float w0 = Ri[0] * t0 + Ri[1] * t1 + Ri[2]  * t2 + Ri[3]  * t3;
  float w1 = Ri[4] * t0 + Ri[5] * t1 + Ri[6]  * t2 + Ri[7]  * t3;
  float w2 = Ri[8] * t0 + Ri[9] * t1 + Ri[10] * t2 + Ri[11] * t3;
  float sp = w0 * w0 + w1 * w1 + w2 * w2;
  pts4[b * PN2 + j] = make_float4(w0, w1, w2, sp);
  float cf = view2 ? dc2[b * PN + jj] : dc1[b * PN + jj];
  lc[b * PN2 + j] = logf(cf + 1e-6f);
}

// Brute-force 4-NN scan. 8 queries/thread amortize each LDS broadcast read
// over 32 VALU ops -> VALU-bound instead of LDS-pipe-bound.
// grid = 8 * ksplit blocks of 256 threads.
__global__ __launch_bounds__(256) void k_knn_scan(
    const float4* __restrict__ pts4,
    float4* __restrict__ psv, int4* __restrict__ pid,
    int ksplit, int cps) {
  int qblk = blockIdx.x & 7;            // 8 query blocks (2048 queries each)
  int split = blockIdx.x >> 3;
  int t = threadIdx.x;
  int b = qblk >> 1;                    // all 2048 queries of a block share b
  const float4* base = pts4 + b * PN2;

  float q2x[QPT], q2y[QPT], q2z[QPT];
  float s0[QPT], s1[QPT], s2[QPT], s3[QPT];
  int i0[QPT], i1[QPT], i2[QPT], i3[QPT];
#pragma unroll
  for (int r = 0; r < QPT; ++r) {
    int Q = qblk * 2048 + r * 256 + t;
    int m = Q & (PN - 1);
    float4 q = base[2 * m];
    q2x[r] = -2.0f * q.x; q2y[r] = -2.0f * q.y; q2z[r] = -2.0f * q.z;
    s0[r] = INFINITY; s1[r] = INFINITY; s2[r] = INFINITY; s3[r] = INFINITY;
    i0[r] = 0x7fffffff; i1[r] = 0x7fffffff; i2[r] = 0x7fffffff; i3[r] = 0x7fffffff;
  }

  __shared__ float4 tile[KTILE];
  int cbase = split * cps;
  for (int tb = 0; tb < cps; tb += KTILE) {
    tile[t] = base[cbase + tb + t];     // KTILE == blockDim.x
    __syncthreads();
#pragma unroll 4
    for (int ct = 0; ct < KTILE; ++ct) {
      float4 p = tile[ct];   // same address across wave -> LDS broadcast
      int cidx = cbase + tb + ct;
#pragma unroll
      for (int r = 0; r < QPT; ++r) {
        float s = fmaf(q2x[r], p.x, fmaf(q2y[r], p.y, fmaf(q2z[r], p.z, p.w)));
        if (s < s3[r])
          ins4(s, cidx, s0[r], s1[r], s2[r], s3[r], i0[r], i1[r], i2[r], i3[r]);
      }
    }
    __syncthreads();
  }
#pragma unroll
  for (int r = 0; r < QPT; ++r) {
    int Q = qblk * 2048 + r * 256 + t;
    psv[split * QTOT + Q] = make_float4(s0[r], s1[r], s2[r], s3[r]);
    pid[split * QTOT + Q] = make_int4(i0[r], i1[r], i2[r], i3[r]);
  }
}

// Merge partial top-4s, softmax weights, blend points, project, zbuf pass 1.
__global__ __launch_bounds__(256) void k_merge_project(
    const float4* __restrict__ pts4, const float* __restrict__ lc,
    const float4* __restrict__ psv, const int4* __restrict__ pid,
    const float* __restrict__ Kmat, const float* __restrict__ oRT,
    int* __restrict__ zbuf,
    int* __restrict__ pixA, float* __restrict__ zA,
    float4* __restrict__ wA, int4* __restrict__ nnA, int ksplit) {
  int Q = blockIdx.x * blockDim.x + threadIdx.x;
  if (Q >= QTOT) return;
  int b = Q >> 12;
  float s0 = INFINITY, s1 = INFINITY, s2 = INFINITY, s3 = INFINITY;
  int i0 = 0, i1 = 0, i2 = 0, i3 = 0;
  // splits in ascending index order preserves lowest-index tie-break
  for (int sp = 0; sp < ksplit; ++sp) {
    float4 sv4 = psv[sp * QTOT + Q];
    int4 iv4 = pid[sp * QTOT + Q];
    if (sv4.x < s3) ins4(sv4.x, iv4.x, s0, s1, s2, s3, i0, i1, i2, i3);
    if (sv4.y < s3) ins4(sv4.y, iv4.y, s0, s1, s2, s3, i0, i1, i2, i3);
    if (sv4.z < s3) ins4(sv4.z, iv4.z, s0, s1, s2, s3, i0, i1, i2, i3);
    if (sv4.w < s3) ins4(sv4.w, iv4.w, s0, s1, s2, s3, i0, i1, i2, i3);
  }
  const float4* base = pts4 + b * PN2;
  int m = Q & (PN - 1);
  float qsq = base[2 * m].w;
  // logits = -10*d2 + log(conf+1e-6);  d2 = |q|^2 + s
  const float* lcb = lc + b * PN2;
  float g0 = -10.0f * (s0 + qsq) + lcb[i0];
  float g1 = -10.0f * (s1 + qsq) + lcb[i1];
  float g2 = -10.0f * (s2 + qsq) + lcb[i2];
  float g3 = -10.0f * (s3 + qsq) + lcb[i3];
  float mx = fmaxf(fmaxf(g0, g1), fmaxf(g2, g3));
  float e0 = expf(g0 - mx), e1 = expf(g1 - mx), e2 = expf(g2 - mx), e3 = expf(g3 - mx);
  float inv = 1.0f / (e0 + e1 + e2 + e3);
  float w0 = e0 * inv, w1 = e1 * inv, w2 = e2 * inv, w3 = e3 * inv;
  float4 p0 = base[i0], p1 = base[i1], p2 = base[i2], p3 = base[i3];
  float fx = w0 * p0.x + w1 * p1.x + w2 * p2.x + w3 * p3.x;
  float fy = w0 * p0.y + w1 * p1.y + w2 * p2.y + w3 * p3.y;
  float fz = w0 * p0.z + w1 * p1.z + w2 * p2.z + w3 * p3.z;
  // xyp = K @ (output_RT @ [fx,fy,fz,1])
  const float* R = oRT + b * 16;
  const float* Km = Kmat + b * 16;
  float t0 = R[0] * fx + R[1] * fy + R[2]  * fz + R[3];
  float t1 = R[4] * fx + R[5] * fy + R[6]  * fz + R[7];
  float t2 = R[8] * fx + R[9] * fy + R[10] * fz + R[11];
  float t3 = R[12] * fx + R[13] * fy + R[14] * fz + R[15];
  float x0 = Km[0] * t0 + Km[1] * t1 + Km[2]  * t2 + Km[3]  * t3;
  float x1 = Km[4] * t0 + Km[5] * t1 + Km[6]  * t2 + Km[7]  * t3;
  float x2 = Km[8] * t0 + Km[9] * t1 + Km[10] * t2 + Km[11] * t3;
  float z = x2;
  bool msk = fabsf(z) < 0.01f;
  float zs = msk ? 0.01f : z;
  float sx, sy, szv;
  if (msk) { sx = 10.0f; sy = 10.0f; szv = 10.0f; }
  else {
    sx = -(x0 * 2.0f / zs / 63.0f - 1.0f);
    sy = -(x1 * 2.0f / zs / 63.0f - 1.0f);
    szv = z;
  }
  int u = (int)rintf((sx + 1.0f) * 0.5f * 63.0f);   // round-half-even like jnp.round
  int v = (int)rintf((sy + 1.0f) * 0.5f * 63.0f);
  bool valid = (u >= 0) && (u < PW) && (v >= 0) && (v < PW) &&
               (szv > 0.005f) && (sx < 9.0f);
  int pix = valid ? (b * PN + v * PW + u) : -1;
  if (valid) atomicMin(&zbuf[pix], __float_as_int(szv)); // z>0: int order == float order
  pixA[Q] = pix;
  zA[Q] = szv;
  wA[Q] = make_float4(w0, w1, w2, w3);
  nnA[Q] = make_int4(i0, i1, i2, i3);
}

// Winner check + feature blend + scatter-add. One WAVE per query; lane = channel.
__global__ __launch_bounds__(256) void k_splat(
    const int* __restrict__ pixA, const float* __restrict__ zA,
    const float4* __restrict__ wA, const int4* __restrict__ nnA,
    const int* __restrict__ zbuf,
    const float* __restrict__ fea1, const float* __restrict__ fea2,
    float* __restrict__ out) {
  int wid = (blockIdx.x * 256 + threadIdx.x) >> 6;   // query id
  int lane = threadIdx.x & 63;                        // channel id
  if (wid >= QTOT) return;
  int pix = pixA[wid];            // wave-uniform
  if (pix < 0) return;
  float z = zA[wid];
  if (__float_as_int(z) != zbuf[pix]) return;  // not a z-buffer winner
  int b = wid >> 12;
  int pl = pix & (PN - 1);
  float4 w = wA[wid];
  int4 nn = nnA[wid];
  const float* f0 = (nn.x < PN ? fea1 : fea2) + b * PC * PN + (nn.x & (PN - 1));
  const float* f1 = (nn.y < PN ? fea1 : fea2) + b * PC * PN + (nn.y & (PN - 1));
  const float* f2 = (nn.z < PN ? fea1 : fea2) + b * PC * PN + (nn.z & (PN - 1));
  const float* f3 = (nn.w < PN ? fea1 : fea2) + b * PC * PN + (nn.w & (PN - 1));
  int co = lane * PN;
  float f = w.x * f0[co] + w.y * f1[co] + w.z * f2[co] + w.w * f3[co];
  float* dst = (lane < 3)
      ? (out + (b * 3 + lane) * PN + pl)
      : (out + POFF1 + (b * 61 + (lane - 3)) * PN + pl);
  atomicAdd(dst, f);
  if (lane == 0) atomicAdd(out + POFF2 + b * PN + pl, z);
}

extern "C" void kernel_launch(void* const* d_in, const int* in_sizes, int n_in,
                              void* d_out, int out_size, void* d_ws, size_t ws_size,
                              hipStream_t stream) {
  const float* fea1   = (const float*)d_in[0];
  const float* fea2   = (const float*)d_in[1];
  const float* pp1    = (const float*)d_in[2];
  const float* pp2    = (const float*)d_in[3];
  const float* Kmat   = (const float*)d_in[4];
  const float* Kinv   = (const float*)d_in[5];
  const float* RTinv1 = (const float*)d_in[8];
  const float* RTinv2 = (const float*)d_in[9];
  const float* oRT    = (const float*)d_in[10];
  const float* dc1    = (const float*)d_in[12];
  const float* dc2    = (const float*)d_in[13];

  char* ws = (char*)d_ws;
  float4* pts4 = (float4*)(ws + 0);
  float*  lc   = (float*)(ws + 524288);
  int*    zbuf = (int*)(ws + 655360);
  int*    pixA = (int*)(ws + 720896);
  float*  zA   = (float*)(ws + 786432);
  float4* wA   = (float4*)(ws + 851968);
  int4*   nnA  = (int4*)(ws + 1114112);
  // candidate split: largest power of 2 whose partial buffers fit in ws
  size_t fixed = 1376256;
  int ksplit = 1;
  for (int k = 32; k >= 2; k >>= 1) {
    if (ws_size >= fixed + (size_t)k * 2 * 262144) { ksplit = k; break; }
  }
  int cps = PN2 / ksplit;
  float4* psv = (float4*)(ws + fixed);
  int4*   pid = (int4*)(ws + fixed + (size_t)ksplit * 262144);
  float*  out = (float*)d_out;

  k_prep<<<(PB * PN2) / 256, 256, 0, stream>>>(pp1, pp2, Kinv, RTinv1, RTinv2,
                                               dc1, dc2, pts4, lc, out, zbuf);
  k_knn_scan<<<8 * ksplit, 256, 0, stream>>>(pts4, psv, pid, ksplit, cps);
  k_merge_project<<<QTOT / 256, 256, 0, stream>>>(pts4, lc, psv, pid, Kmat, oRT,
                                                  zbuf, pixA, zA, wA, nnA, ksplit);
  k_splat<<<(QTOT * 64) / 256, 256, 0, stream>>>(pixA, zA, wA, nnA, zbuf,
                                                 fea1, fea2, out);
}

// Round 5
// 372.748 us; speedup vs baseline: 3.3233x; 3.3233x over previous
//
#include <hip/hip_runtime.h>
#include <math.h>

// Problem constants (B=4, C=64, W=64 from reference)
#define PB 4
#define PC 64
#define PW 64
#define PN 4096      // W*W
#define PN2 8192     // 2*N (candidates per batch)
#define QTOT 16384   // B*N queries
#define KTILE 256    // candidates staged in LDS per tile
#define POFF1 49152      // 4*3*4096  (res[:, :3] size)
#define POFF2 1048576    // POFF1 + 4*61*4096 (start of depth)
#define OUTSZ 1064960    // POFF2 + 4*4096

// ---- workspace layout (bytes) ----
// pts4 : 0        .. 524288    (B*2N float4: x,y,z,|p|^2)
// lc   : 524288   .. 655360    (B*2N float: log(conf+1e-6))
// zbuf : 655360   .. 720896    (B*N int, float bits, init +inf)
// pixA : 720896   .. 786432    (QTOT int, dest pixel or -1)
// zA   : 786432   .. 851968    (QTOT float, splat z)
// wA   : 851968   .. 1114112   (QTOT float4, softmax weights)
// nnA  : 1114112  .. 1376256   (QTOT int4, neighbor indices)
// psv  : 1376256  .. +ksplit*262144  (float4 partial top-4 dists)
// pid  : after psv .. +ksplit*262144 (int4 partial top-4 idx)

__device__ __forceinline__ void ins4(float s, int idx,
    float& s0, float& s1, float& s2, float& s3,
    int& i0, int& i1, int& i2, int& i3) {
  // caller guarantees s < s3; strict < keeps lowest-index-first tie-break
  if (s < s2) {
    s3 = s2; i3 = i2;
    if (s < s1) {
      s2 = s1; i2 = i1;
      if (s < s0) { s1 = s0; i1 = i0; s0 = s; i0 = idx; }
      else        { s1 = s;  i1 = idx; }
    } else { s2 = s; i2 = idx; }
  } else { s3 = s; i3 = idx; }
}

// Fused: zero output, init zbuf to +inf, unproject both views to world
// points (x,y,z,|p|^2) and log(conf+1e-6).
__global__ __launch_bounds__(256) void k_prep(
    const float* __restrict__ pp1, const float* __restrict__ pp2,
    const float* __restrict__ Kinv,
    const float* __restrict__ RTinv1, const float* __restrict__ RTinv2,
    const float* __restrict__ dc1, const float* __restrict__ dc2,
    float4* __restrict__ pts4, float* __restrict__ lc,
    float* __restrict__ out, int* __restrict__ zbuf) {
  int gid = blockIdx.x * blockDim.x + threadIdx.x;   // 0 .. 32767
  int stride = gridDim.x * blockDim.x;
  for (int j = gid; j < OUTSZ; j += stride) out[j] = 0.0f;
  if (gid < PB * PN) zbuf[gid] = 0x7f800000;          // +inf

  // one world point per thread
  int b = gid >> 13;                 // gid / PN2
  int j = gid & (PN2 - 1);
  int view2 = (j >= PN) ? 1 : 0;
  int jj = view2 ? (j - PN) : j;
  float d = view2 ? pp2[b * PN + jj] : pp1[b * PN + jj];
  float x = (float)(jj & (PW - 1));
  float y = (float)(jj >> 6);
  const float* Ki = Kinv + b * 16;
  const float* Ri = (view2 ? RTinv2 : RTinv1) + b * 16;
  // proj = [x*d, y*d, d, 1]
  float p0 = x * d, p1 = y * d, p2 = d, p3 = 1.0f;
  float t0 = Ki[0]  * p0 + Ki[1]  * p1 + Ki[2]  * p2 + Ki[3]  * p3;
  float t1 = Ki[4]  * p0 + Ki[5]  * p1 + Ki[6]  * p2 + Ki[7]  * p3;
  float t2 = Ki[8]  * p0 + Ki[9]  * p1 + Ki[10] * p2 + Ki[11] * p3;
  float t3 = Ki[12] * p0 + Ki[13] * p1 + Ki[14] * p2 + Ki[15] * p3;
  float w0 = Ri[0] * t0 + Ri[1] * t1 + Ri[2]  * t2 + Ri[3]  * t3;
  float w1 = Ri[4] * t0 + Ri[5] * t1 + Ri[6]  * t2 + Ri[7]  * t3;
  float w2 = Ri[8] * t0 + Ri[9] * t1 + Ri[10] * t2 + Ri[11] * t3;
  float sp = w0 * w0 + w1 * w1 + w2 * w2;
  pts4[b * PN2 + j] = make_float4(w0, w1, w2, sp);
  float cf = view2 ? dc2[b * PN + jj] : dc1[b * PN + jj];
  lc[b * PN2 + j] = logf(cf + 1e-6f);
}

// Brute-force 4-NN scan, 8 queries/thread. ALL per-query state is named
// scalars via macro expansion — nothing address-taken, nothing array-indexed,
// so the compiler cannot demote it to scratch (round-3 post-mortem: QPT
// arrays + ins4(float&) refs => VGPR_Count=20, 210 MB scratch traffic,
// 1086 us; this version must show VGPR ~110+, WRITE_SIZE ~17 MB).
#define FOR8(X) X(0) X(1) X(2) X(3) X(4) X(5) X(6) X(7)

#define INS4N(s, idx, sA, sB, sC, sD, iA, iB, iC, iD) \
  if (s < sC) { sD = sC; iD = iC;                      \
    if (s < sB) { sC = sB; iC = iB;                    \
      if (s < sA) { sB = sA; iB = iA; sA = s; iA = idx; } \
      else        { sB = s;  iB = idx; }               \
    } else { sC = s; iC = idx; }                       \
  } else { sD = s; iD = idx; }

__global__ __launch_bounds__(256) void k_knn_scan(
    const float4* __restrict__ pts4,
    float4* __restrict__ psv, int4* __restrict__ pid,
    int ksplit, int cps) {
  int qblk = blockIdx.x & 7;            // 8 query blocks (2048 queries each)
  int split = blockIdx.x >> 3;
  int t = threadIdx.x;
  int b = qblk >> 1;                    // all 2048 queries of a block share b
  const float4* base = pts4 + b * PN2;

#define QDECL(r)                                                        \
  float q2x##r, q2y##r, q2z##r;                                         \
  float sA##r = INFINITY, sB##r = INFINITY,                             \
        sC##r = INFINITY, sD##r = INFINITY;                             \
  int iA##r = 0x7fffffff, iB##r = 0x7fffffff,                           \
      iC##r = 0x7fffffff, iD##r = 0x7fffffff;                           \
  {                                                                     \
    int m = (qblk * 2048 + r * 256 + t) & (PN - 1);                     \
    float4 q = base[2 * m];                                             \
    q2x##r = -2.0f * q.x; q2y##r = -2.0f * q.y; q2z##r = -2.0f * q.z;   \
  }
  FOR8(QDECL)

  __shared__ float4 tile[KTILE];
  int cbase = split * cps;
  for (int tb = 0; tb < cps; tb += KTILE) {
    tile[t] = base[cbase + tb + t];     // KTILE == blockDim.x
    __syncthreads();
#pragma unroll 4
    for (int ct = 0; ct < KTILE; ++ct) {
      float4 p = tile[ct];   // same address across wave -> LDS broadcast
      int cidx = cbase + tb + ct;
#define QBODY(r) {                                                          \
      float s = fmaf(q2x##r, p.x, fmaf(q2y##r, p.y, fmaf(q2z##r, p.z, p.w))); \
      if (s < sD##r) {                                                      \
        INS4N(s, cidx, sA##r, sB##r, sC##r, sD##r,                          \
              iA##r, iB##r, iC##r, iD##r)                                   \
      } }
      FOR8(QBODY)
    }
    __syncthreads();
  }
#define QSTORE(r) {                                                     \
    int Q = qblk * 2048 + r * 256 + t;                                  \
    psv[split * QTOT + Q] = make_float4(sA##r, sB##r, sC##r, sD##r);    \
    pid[split * QTOT + Q] = make_int4(iA##r, iB##r, iC##r, iD##r);      \
  }
  FOR8(QSTORE)
}

// Merge partial top-4s, softmax weights, blend points, project, zbuf pass 1.
__global__ __launch_bounds__(256) void k_merge_project(
    const float4* __restrict__ pts4, const float* __restrict__ lc,
    const float4* __restrict__ psv, const int4* __restrict__ pid,
    const float* __restrict__ Kmat, const float* __restrict__ oRT,
    int* __restrict__ zbuf,
    int* __restrict__ pixA, float* __restrict__ zA,
    float4* __restrict__ wA, int4* __restrict__ nnA, int ksplit) {
  int Q = blockIdx.x * blockDim.x + threadIdx.x;
  if (Q >= QTOT) return;
  int b = Q >> 12;
  float s0 = INFINITY, s1 = INFINITY, s2 = INFINITY, s3 = INFINITY;
  int i0 = 0, i1 = 0, i2 = 0, i3 = 0;
  // splits in ascending index order preserves lowest-index tie-break
  for (int sp = 0; sp < ksplit; ++sp) {
    float4 sv4 = psv[sp * QTOT + Q];
    int4 iv4 = pid[sp * QTOT + Q];
    if (sv4.x < s3) ins4(sv4.x, iv4.x, s0, s1, s2, s3, i0, i1, i2, i3);
    if (sv4.y < s3) ins4(sv4.y, iv4.y, s0, s1, s2, s3, i0, i1, i2, i3);
    if (sv4.z < s3) ins4(sv4.z, iv4.z, s0, s1, s2, s3, i0, i1, i2, i3);
    if (sv4.w < s3) ins4(sv4.w, iv4.w, s0, s1, s2, s3, i0, i1, i2, i3);
  }
  const float4* base = pts4 + b * PN2;
  int m = Q & (PN - 1);
  float qsq = base[2 * m].w;
  // logits = -10*d2 + log(conf+1e-6);  d2 = |q|^2 + s
  const float* lcb = lc + b * PN2;
  float g0 = -10.0f * (s0 + qsq) + lcb[i0];
  float g1 = -10.0f * (s1 + qsq) + lcb[i1];
  float g2 = -10.0f * (s2 + qsq) + lcb[i2];
  float g3 = -10.0f * (s3 + qsq) + lcb[i3];
  float mx = fmaxf(fmaxf(g0, g1), fmaxf(g2, g3));
  float e0 = expf(g0 - mx), e1 = expf(g1 - mx), e2 = expf(g2 - mx), e3 = expf(g3 - mx);
  float inv = 1.0f / (e0 + e1 + e2 + e3);
  float w0 = e0 * inv, w1 = e1 * inv, w2 = e2 * inv, w3 = e3 * inv;
  float4 p0 = base[i0], p1 = base[i1], p2 = base[i2], p3 = base[i3];
  float fx = w0 * p0.x + w1 * p1.x + w2 * p2.x + w3 * p3.x;
  float fy = w0 * p0.y + w1 * p1.y + w2 * p2.y + w3 * p3.y;
  float fz = w0 * p0.z + w1 * p1.z + w2 * p2.z + w3 * p3.z;
  // xyp = K @ (output_RT @ [fx,fy,fz,1])
  const float* R = oRT + b * 16;
  const float* Km = Kmat + b * 16;
  float t0 = R[0] * fx + R[1] * fy + R[2]  * fz + R[3];
  float t1 = R[4] * fx + R[5] * fy + R[6]  * fz + R[7];
  float t2 = R[8] * fx + R[9] * fy + R[10] * fz + R[11];
  float t3 = R[12] * fx + R[13] * fy + R[14] * fz + R[15];
  float x0 = Km[0] * t0 + Km[1] * t1 + Km[2]  * t2 + Km[3]  * t3;
  float x1 = Km[4] * t0 + Km[5] * t1 + Km[6]  * t2 + Km[7]  * t3;
  float x2 = Km[8] * t0 + Km[9] * t1 + Km[10] * t2 + Km[11] * t3;
  float z = x2;
  bool msk = fabsf(z) < 0.01f;
  float zs = msk ? 0.01f : z;
  float sx, sy, szv;
  if (msk) { sx = 10.0f; sy = 10.0f; szv = 10.0f; }
  else {
    sx = -(x0 * 2.0f / zs / 63.0f - 1.0f);
    sy = -(x1 * 2.0f / zs / 63.0f - 1.0f);
    szv = z;
  }
  int u = (int)rintf((sx + 1.0f) * 0.5f * 63.0f);   // round-half-even like jnp.round
  int v = (int)rintf((sy + 1.0f) * 0.5f * 63.0f);
  bool valid = (u >= 0) && (u < PW) && (v >= 0) && (v < PW) &&
               (szv > 0.005f) && (sx < 9.0f);
  int pix = valid ? (b * PN + v * PW + u) : -1;
  if (valid) atomicMin(&zbuf[pix], __float_as_int(szv)); // z>0: int order == float order
  pixA[Q] = pix;
  zA[Q] = szv;
  wA[Q] = make_float4(w0, w1, w2, w3);
  nnA[Q] = make_int4(i0, i1, i2, i3);
}

// Winner check + feature blend + scatter-add. One WAVE per query; lane = channel.
__global__ __launch_bounds__(256) void k_splat(
    const int* __restrict__ pixA, const float* __restrict__ zA,
    const float4* __restrict__ wA, const int4* __restrict__ nnA,
    const int* __restrict__ zbuf,
    const float* __restrict__ fea1, const float* __restrict__ fea2,
    float* __restrict__ out) {
  int wid = (blockIdx.x * 256 + threadIdx.x) >> 6;   // query id
  int lane = threadIdx.x & 63;                        // channel id
  if (wid >= QTOT) return;
  int pix = pixA[wid];            // wave-uniform
  if (pix < 0) return;
  float z = zA[wid];
  if (__float_as_int(z) != zbuf[pix]) return;  // not a z-buffer winner
  int b = wid >> 12;
  int pl = pix & (PN - 1);
  float4 w = wA[wid];
  int4 nn = nnA[wid];
  const float* f0 = (nn.x < PN ? fea1 : fea2) + b * PC * PN + (nn.x & (PN - 1));
  const float* f1 = (nn.y < PN ? fea1 : fea2) + b * PC * PN + (nn.y & (PN - 1));
  const float* f2 = (nn.z < PN ? fea1 : fea2) + b * PC * PN + (nn.z & (PN - 1));
  const float* f3 = (nn.w < PN ? fea1 : fea2) + b * PC * PN + (nn.w & (PN - 1));
  int co = lane * PN;
  float f = w.x * f0[co] + w.y * f1[co] + w.z * f2[co] + w.w * f3[co];
  float* dst = (lane < 3)
      ? (out + (b * 3 + lane) * PN + pl)
      : (out + POFF1 + (b * 61 + (lane - 3)) * PN + pl);
  atomicAdd(dst, f);
  if (lane == 0) atomicAdd(out + POFF2 + b * PN + pl, z);
}

extern "C" void kernel_launch(void* const* d_in, const int* in_sizes, int n_in,
                              void* d_out, int out_size, void* d_ws, size_t ws_size,
                              hipStream_t stream) {
  const float* fea1   = (const float*)d_in[0];
  const float* fea2   = (const float*)d_in[1];
  const float* pp1    = (const float*)d_in[2];
  const float* pp2    = (const float*)d_in[3];
  const float* Kmat   = (const float*)d_in[4];
  const float* Kinv   = (const float*)d_in[5];
  const float* RTinv1 = (const float*)d_in[8];
  const float* RTinv2 = (const float*)d_in[9];
  const float* oRT    = (const float*)d_in[10];
  const float* dc1    = (const float*)d_in[12];
  const float* dc2    = (const float*)d_in[13];

  char* ws = (char*)d_ws;
  float4* pts4 = (float4*)(ws + 0);
  float*  lc   = (float*)(ws + 524288);
  int*    zbuf = (int*)(ws + 655360);
  int*    pixA = (int*)(ws + 720896);
  float*  zA   = (float*)(ws + 786432);
  float4* wA   = (float4*)(ws + 851968);
  int4*   nnA  = (int4*)(ws + 1114112);
  // candidate split: largest power of 2 whose partial buffers fit in ws
  size_t fixed = 1376256;
  int ksplit = 1;
  for (int k = 32; k >= 2; k >>= 1) {
    if (ws_size >= fixed + (size_t)k * 2 * 262144) { ksplit = k; break; }
  }
  int cps = PN2 / ksplit;
  float4* psv = (float4*)(ws + fixed);
  int4*   pid = (int4*)(ws + fixed + (size_t)ksplit * 262144);
  float*  out = (float*)d_out;

  k_prep<<<(PB * PN2) / 256, 256, 0, stream>>>(pp1, pp2, Kinv, RTinv1, RTinv2,
                                               dc1, dc2, pts4, lc, out, zbuf);
  k_knn_scan<<<8 * ksplit, 256, 0, stream>>>(pts4, psv, pid, ksplit, cps);
  k_merge_project<<<QTOT / 256, 256, 0, stream>>>(pts4, lc, psv, pid, Kmat, oRT,
                                                  zbuf, pixA, zA, wA, nnA, ksplit);
  k_splat<<<(QTOT * 64) / 256, 256, 0, stream>>>(pixA, zA, wA, nnA, zbuf,
                                                 fea1, fea2, out);
}

// Round 9
// 202.899 us; speedup vs baseline: 6.1053x; 1.8371x over previous
//
#include <hip/hip_runtime.h>
#include <math.h>

// Problem constants (B=4, C=64, W=64 from reference)
#define PB 4
#define PC 64
#define PW 64
#define PN 4096      // W*W
#define PN2 8192     // 2*N (candidates per batch)
#define QTOT 16384   // B*N queries
#define KTILE 256    // candidates staged in LDS per tile
#define POFF1 49152      // 4*3*4096  (res[:, :3] size)
#define POFF2 1048576    // POFF1 + 4*61*4096 (start of depth)
#define OUTSZ 1064960    // POFF2 + 4*4096

// ---- workspace layout (bytes) ----
// pts4 : 0        .. 524288    (B*2N float4: x,y,z,|p|^2)
// lc   : 524288   .. 655360    (B*2N float: log(conf+1e-6))
// zbuf : 655360   .. 720896    (B*N int, float bits, init +inf)
// pixA : 720896   .. 786432    (QTOT int, dest pixel or -1)
// zA   : 786432   .. 851968    (QTOT float, splat z)
// wA   : 851968   .. 1114112   (QTOT float4, softmax weights)
// nnA  : 1114112  .. 1376256   (QTOT int4, neighbor indices)
// psv  : 1376256  .. +ksplit*262144  (float4 partial top-4 dists)
// pid  : after psv .. +ksplit*262144 (int4 partial top-4 idx)

// Fused: zero output, init zbuf to +inf, unproject both views to world
// points (x,y,z,|p|^2) and log(conf+1e-6).
__global__ __launch_bounds__(256) void k_prep(
    const float* __restrict__ pp1, const float* __restrict__ pp2,
    const float* __restrict__ Kinv,
    const float* __restrict__ RTinv1, const float* __restrict__ RTinv2,
    const float* __restrict__ dc1, const float* __restrict__ dc2,
    float4* __restrict__ pts4, float* __restrict__ lc,
    float* __restrict__ out, int* __restrict__ zbuf) {
  int gid = blockIdx.x * blockDim.x + threadIdx.x;   // 0 .. 32767
  int stride = gridDim.x * blockDim.x;
  for (int j = gid; j < OUTSZ; j += stride) out[j] = 0.0f;
  if (gid < PB * PN) zbuf[gid] = 0x7f800000;          // +inf

  // one world point per thread
  int b = gid >> 13;                 // gid / PN2
  int j = gid & (PN2 - 1);
  int view2 = (j >= PN) ? 1 : 0;
  int jj = view2 ? (j - PN) : j;
  float d = view2 ? pp2[b * PN + jj] : pp1[b * PN + jj];
  float x = (float)(jj & (PW - 1));
  float y = (float)(jj >> 6);
  const float* Ki = Kinv + b * 16;
  const float* Ri = (view2 ? RTinv2 : RTinv1) + b * 16;
  // proj = [x*d, y*d, d, 1]
  float p0 = x * d, p1 = y * d, p2 = d, p3 = 1.0f;
  float t0 = Ki[0]  * p0 + Ki[1]  * p1 + Ki[2]  * p2 + Ki[3]  * p3;
  float t1 = Ki[4]  * p0 + Ki[5]  * p1 + Ki[6]  * p2 + Ki[7]  * p3;
  float t2 = Ki[8]  * p0 + Ki[9]  * p1 + Ki[10] * p2 + Ki[11] * p3;
  float t3 = Ki[12] * p0 + Ki[13] * p1 + Ki[14] * p2 + Ki[15] * p3;
  float w0 = Ri[0] * t0 + Ri[1] * t1 + Ri[2]  * t2 + Ri[3]  * t3;
  float w1 = Ri[4] * t0 + Ri[5] * t1 + Ri[6]  * t2 + Ri[7]  * t3;
  float w2 = Ri[8] * t0 + Ri[9] * t1 + Ri[10] * t2 + Ri[11] * t3;
  float sp = w0 * w0 + w1 * w1 + w2 * w2;
  pts4[b * PN2 + j] = make_float4(w0, w1, w2, sp);
  float cf = view2 ? dc2[b * PN + jj] : dc1[b * PN + jj];
  lc[b * PN2 + j] = logf(cf + 1e-6f);
}

// ---------------- KNN scan ----------------
// Round-5 post-mortem: nested-branch insert was if-converted anyway (33 VALU
// instrs/body) and 1 wave/SIMD left it latency-bound (VALUBusy 29%).
// Now: explicitly branchless sorted-displacement insert (~21 instrs/body,
// pure cndmask dataflow) + 512-thr blocks, QPT=2, grid 16*ksplit -> 16
// waves/CU. Set-semantics match reference (blend is order-symmetric in k).
#define FOR2(X) X(0) X(1)

__global__ __launch_bounds__(512) void k_knn_scan(
    const float4* __restrict__ pts4,
    float4* __restrict__ psv, int4* __restrict__ pid,
    int ksplit, int cps) {
  int qblk = blockIdx.x & 15;           // 16 query blocks (1024 queries each)
  int split = blockIdx.x >> 4;
  int t = threadIdx.x;                  // 0..511
  int b = qblk >> 2;                    // batch (1024 queries per block, 4096/batch)
  const float4* base = pts4 + b * PN2;

#define QDECL(r)                                                        \
  float q2x##r, q2y##r, q2z##r;                                         \
  float sA##r = INFINITY, sB##r = INFINITY,                             \
        sC##r = INFINITY, sD##r = INFINITY;                             \
  int iA##r = 0x7fffffff, iB##r = 0x7fffffff,                           \
      iC##r = 0x7fffffff, iD##r = 0x7fffffff;                           \
  {                                                                     \
    int m = (qblk * 1024 + r * 512 + t) & (PN - 1);                     \
    float4 q = base[2 * m];                                             \
    q2x##r = -2.0f * q.x; q2y##r = -2.0f * q.y; q2z##r = -2.0f * q.z;   \
  }
  FOR2(QDECL)

  __shared__ float4 tile[KTILE];
  int cbase = split * cps;
  for (int tb = 0; tb < cps; tb += KTILE) {
    __syncthreads();
    if (t < KTILE) tile[t] = base[cbase + tb + t];
    __syncthreads();
#pragma unroll 4
    for (int ct = 0; ct < KTILE; ++ct) {
      float4 p = tile[ct];   // same address across wave -> LDS broadcast
      int cidx = cbase + tb + ct;
      // branchless sorted-displacement insert of (s,cidx) into
      // (sA,iA)<=..<=(sD,iD); strict < so earlier (lower) indices stay up.
#define QBODY(r) {                                                          \
      float s = fmaf(q2x##r, p.x, fmaf(q2y##r, p.y, fmaf(q2z##r, p.z, p.w))); \
      float ts = s; int ti = cidx; bool c; float ns; int ni;                \
      c = ts < sA##r;                                                       \
      ns = c ? sA##r : ts; ni = c ? iA##r : ti;                             \
      sA##r = c ? ts : sA##r; iA##r = c ? ti : iA##r; ts = ns; ti = ni;     \
      c = ts < sB##r;                                                       \
      ns = c ? sB##r : ts; ni = c ? iB##r : ti;                             \
      sB##r = c ? ts : sB##r; iB##r = c ? ti : iB##r; ts = ns; ti = ni;     \
      c = ts < sC##r;                                                       \
      ns = c ? sC##r : ts; ni = c ? iC##r : ti;                             \
      sC##r = c ? ts : sC##r; iC##r = c ? ti : iC##r; ts = ns; ti = ni;     \
      c = ts < sD##r;                                                       \
      sD##r = c ? ts : sD##r; iD##r = c ? ti : iD##r; }
      FOR2(QBODY)
    }
  }
#define QSTORE(r) {                                                     \
    int Q = qblk * 1024 + r * 512 + t;                                  \
    psv[split * QTOT + Q] = make_float4(sA##r, sB##r, sC##r, sD##r);    \
    pid[split * QTOT + Q] = make_int4(iA##r, iB##r, iC##r, iD##r);      \
  }
  FOR2(QSTORE)
}

// ---------------- merge + project ----------------
// 4 threads per query (65536 threads, 256 blocks). Each thread merges
// ksplit/4 splits branchlessly with lexicographic (d2, idx) order (exact
// reference tie-break), then a 2-round shfl_xor butterfly combines the 4.
#define LEXINS(sv, iv)                                                     \
  { float ts = (sv); int ti = (iv); bool c; float ns; int ni;              \
    c = (ts < m0) || ((ts == m0) && (ti < j0));                            \
    ns = c ? m0 : ts; ni = c ? j0 : ti;                                    \
    m0 = c ? ts : m0; j0 = c ? ti : j0; ts = ns; ti = ni;                  \
    c = (ts < m1) || ((ts == m1) && (ti < j1));                            \
    ns = c ? m1 : ts; ni = c ? j1 : ti;                                    \
    m1 = c ? ts : m1; j1 = c ? ti : j1; ts = ns; ti = ni;                  \
    c = (ts < m2) || ((ts == m2) && (ti < j2));                            \
    ns = c ? m2 : ts; ni = c ? j2 : ti;                                    \
    m2 = c ? ts : m2; j2 = c ? ti : j2; ts = ns; ti = ni;                  \
    c = (ts < m3) || ((ts == m3) && (ti < j3));                            \
    m3 = c ? ts : m3; j3 = c ? ti : j3; }

__global__ __launch_bounds__(256) void k_merge_project(
    const float4* __restrict__ pts4, const float* __restrict__ lc,
    const float4* __restrict__ psv, const int4* __restrict__ pid,
    const float* __restrict__ Kmat, const float* __restrict__ oRT,
    int* __restrict__ zbuf,
    int* __restrict__ pixA, float* __restrict__ zA,
    float4* __restrict__ wA, int4* __restrict__ nnA, int ksplit) {
  int gid = blockIdx.x * blockDim.x + threadIdx.x;   // 0..65535
  int Q = gid >> 2;
  int sub = gid & 3;
  int b = Q >> 12;

  float m0 = INFINITY, m1 = INFINITY, m2 = INFINITY, m3 = INFINITY;
  int j0 = 0x7fffffff, j1 = 0x7fffffff, j2 = 0x7fffffff, j3 = 0x7fffffff;
  for (int sp = sub; sp < ksplit; sp += 4) {
    float4 sv4 = psv[sp * QTOT + Q];
    int4 iv4 = pid[sp * QTOT + Q];
    LEXINS(sv4.x, iv4.x)
    LEXINS(sv4.y, iv4.y)
    LEXINS(sv4.z, iv4.z)
    LEXINS(sv4.w, iv4.w)
  }
  // butterfly across the 4 threads of this query (lanes Q*4+sub share a wave)
  for (int d = 1; d <= 2; d <<= 1) {
    float t0 = __shfl_xor(m0, d), t1 = __shfl_xor(m1, d),
          t2 = __shfl_xor(m2, d), t3 = __shfl_xor(m3, d);
    int u0 = __shfl_xor(j0, d), u1 = __shfl_xor(j1, d),
        u2 = __shfl_xor(j2, d), u3 = __shfl_xor(j3, d);
    LEXINS(t0, u0) LEXINS(t1, u1) LEXINS(t2, u2) LEXINS(t3, u3)
  }
  if (sub != 0) return;

  const float4* base = pts4 + b * PN2;
  int m = Q & (PN - 1);
  float qsq = base[2 * m].w;
  // logits = -10*d2 + log(conf+1e-6);  d2 = |q|^2 + s
  const float* lcb = lc + b * PN2;
  float g0 = -10.0f * (m0 + qsq) + lcb[j0];
  float g1 = -10.0f * (m1 + qsq) + lcb[j1];
  float g2 = -10.0f * (m2 + qsq) + lcb[j2];
  float g3 = -10.0f * (m3 + qsq) + lcb[j3];
  float mx = fmaxf(fmaxf(g0, g1), fmaxf(g2, g3));
  float e0 = expf(g0 - mx), e1 = expf(g1 - mx), e2 = expf(g2 - mx), e3 = expf(g3 - mx);
  float inv = 1.0f / (e0 + e1 + e2 + e3);
  float w0 = e0 * inv, w1 = e1 * inv, w2 = e2 * inv, w3 = e3 * inv;
  float4 p0 = base[j0], p1 = base[j1], p2 = base[j2], p3 = base[j3];
  float fx = w0 * p0.x + w1 * p1.x + w2 * p2.x + w3 * p3.x;
  float fy = w0 * p0.y + w1 * p1.y + w2 * p2.y + w3 * p3.y;
  float fz = w0 * p0.z + w1 * p1.z + w2 * p2.z + w3 * p3.z;
  // xyp = K @ (output_RT @ [fx,fy,fz,1])
  const float* R = oRT + b * 16;
  const float* Km = Kmat + b * 16;
  float t0 = R[0] * fx + R[1] * fy + R[2]  * fz + R[3];
  float t1 = R[4] * fx + R[5] * fy + R[6]  * fz + R[7];
  float t2 = R[8] * fx + R[9] * fy + R[10] * fz + R[11];
  float t3 = R[12] * fx + R[13] * fy + R[14] * fz + R[15];
  float x0 = Km[0] * t0 + Km[1] * t1 + Km[2]  * t2 + Km[3]  * t3;
  float x1 = Km[4] * t0 + Km[5] * t1 + Km[6]  * t2 + Km[7]  * t3;
  float x2 = Km[8] * t0 + Km[9] * t1 + Km[10] * t2 + Km[11] * t3;
  float z = x2;
  bool msk = fabsf(z) < 0.01f;
  float zs = msk ? 0.01f : z;
  float sx, sy, szv;
  if (msk) { sx = 10.0f; sy = 10.0f; szv = 10.0f; }
  else {
    sx = -(x0 * 2.0f / zs / 63.0f - 1.0f);
    sy = -(x1 * 2.0f / zs / 63.0f - 1.0f);
    szv = z;
  }
  int u = (int)rintf((sx + 1.0f) * 0.5f * 63.0f);   // round-half-even like jnp.round
  int v = (int)rintf((sy + 1.0f) * 0.5f * 63.0f);
  bool valid = (u >= 0) && (u < PW) && (v >= 0) && (v < PW) &&
               (szv > 0.005f) && (sx < 9.0f);
  int pix = valid ? (b * PN + v * PW + u) : -1;
  if (valid) atomicMin(&zbuf[pix], __float_as_int(szv)); // z>0: int order == float order
  pixA[Q] = pix;
  zA[Q] = szv;
  wA[Q] = make_float4(w0, w1, w2, w3);
  nnA[Q] = make_int4(j0, j1, j2, j3);
}

// Winner check + feature blend + scatter-add. One WAVE per query; lane = channel.
__global__ __launch_bounds__(256) void k_splat(
    const int* __restrict__ pixA, const float* __restrict__ zA,
    const float4* __restrict__ wA, const int4* __restrict__ nnA,
    const int* __restrict__ zbuf,
    const float* __restrict__ fea1, const float* __restrict__ fea2,
    float* __restrict__ out) {
  int wid = (blockIdx.x * 256 + threadIdx.x) >> 6;   // query id
  int lane = threadIdx.x & 63;                        // channel id
  if (wid >= QTOT) return;
  int pix = pixA[wid];            // wave-uniform
  if (pix < 0) return;
  float z = zA[wid];
  if (__float_as_int(z) != zbuf[pix]) return;  // not a z-buffer winner
  int b = wid >> 12;
  int pl = pix & (PN - 1);
  float4 w = wA[wid];
  int4 nn = nnA[wid];
  const float* f0 = (nn.x < PN ? fea1 : fea2) + b * PC * PN + (nn.x & (PN - 1));
  const float* f1 = (nn.y < PN ? fea1 : fea2) + b * PC * PN + (nn.y & (PN - 1));
  const float* f2 = (nn.z < PN ? fea1 : fea2) + b * PC * PN + (nn.z & (PN - 1));
  const float* f3 = (nn.w < PN ? fea1 : fea2) + b * PC * PN + (nn.w & (PN - 1));
  int co = lane * PN;
  float f = w.x * f0[co] + w.y * f1[co] + w.z * f2[co] + w.w * f3[co];
  float* dst = (lane < 3)
      ? (out + (b * 3 + lane) * PN + pl)
      : (out + POFF1 + (b * 61 + (lane - 3)) * PN + pl);
  atomicAdd(dst, f);
  if (lane == 0) atomicAdd(out + POFF2 + b * PN + pl, z);
}

extern "C" void kernel_launch(void* const* d_in, const int* in_sizes, int n_in,
                              void* d_out, int out_size, void* d_ws, size_t ws_size,
                              hipStream_t stream) {
  const float* fea1   = (const float*)d_in[0];
  const float* fea2   = (const float*)d_in[1];
  const float* pp1    = (const float*)d_in[2];
  const float* pp2    = (const float*)d_in[3];
  const float* Kmat   = (const float*)d_in[4];
  const float* Kinv   = (const float*)d_in[5];
  const float* RTinv1 = (const float*)d_in[8];
  const float* RTinv2 = (const float*)d_in[9];
  const float* oRT    = (const float*)d_in[10];
  const float* dc1    = (const float*)d_in[12];
  const float* dc2    = (const float*)d_in[13];

  char* ws = (char*)d_ws;
  float4* pts4 = (float4*)(ws + 0);
  float*  lc   = (float*)(ws + 524288);
  int*    zbuf = (int*)(ws + 655360);
  int*    pixA = (int*)(ws + 720896);
  float*  zA   = (float*)(ws + 786432);
  float4* wA   = (float4*)(ws + 851968);
  int4*   nnA  = (int4*)(ws + 1114112);
  // candidate split: largest power of 2 whose partial buffers fit in ws
  size_t fixed = 1376256;
  int ksplit = 1;
  for (int k = 32; k >= 2; k >>= 1) {
    if (ws_size >= fixed + (size_t)k * 2 * 262144) { ksplit = k; break; }
  }
  int cps = PN2 / ksplit;
  float4* psv = (float4*)(ws + fixed);
  int4*   pid = (int4*)(ws + fixed + (size_t)ksplit * 262144);
  float*  out = (float*)d_out;

  k_prep<<<(PB * PN2) / 256, 256, 0, stream>>>(pp1, pp2, Kinv, RTinv1, RTinv2,
                                               dc1, dc2, pts4, lc, out, zbuf);
  k_knn_scan<<<16 * ksplit, 512, 0, stream>>>(pts4, psv, pid, ksplit, cps);
  k_merge_project<<<(QTOT * 4) / 256, 256, 0, stream>>>(pts4, lc, psv, pid,
                                                        Kmat, oRT, zbuf, pixA,
                                                        zA, wA, nnA, ksplit);
  k_splat<<<(QTOT * 64) / 256, 256, 0, stream>>>(pixA, zA, wA, nnA, zbuf,
                                                 fea1, fea2, out);
}